// Round 4
// baseline (85.262 us; speedup 1.0000x reference)
//
#include <hip/hip_runtime.h>
#include <math.h>

// L=13, M=12, ODD_KS=(1,3,5) -> NK=3
#define LL   13
#define MM   12
#define NKK  3
#define BLOCK 256
#define HALO  24                 // window spans [t-24, t+24]
#define WIN  (BLOCK + 2*HALO)    // 304 samples staged per block

typedef float v2f __attribute__((ext_vector_type(2)));  // -> v_pk_fma_f32

// LDS index map (window base t0-24), i = tid:
//   x1(l)    -> Z[i + l + 12]      B-powers(l,m) -> P[i + l + m]
//   x3l(l)   -> Z[i + l + 36]      C-powers(l,m) -> P[i + l + m + 24]
// out = sum_l x1*(A[l].p1 + sum_m B[l,m].P) + x3last*(sum_m C[l,m].P')

__global__ __launch_bounds__(BLOCK)
void gmp_kernel(const float* __restrict__ x,    // (B,T,2)
                const float* __restrict__ Ac,   // (L,NK)
                const float* __restrict__ Bc,   // (L,M,NK)
                const float* __restrict__ Cc,   // (L,M,NK)
                float* __restrict__ out,        // (B,T,2)
                int T, int tilesPerB)
{
    __shared__ float4 sP[WIN];   // {a, a^3, a^5, 0} -> ds_read_b128
    __shared__ float2 sZ[WIN];   // {re, im}         -> ds_read_b64

    const int tid = threadIdx.x;
    const int b   = blockIdx.x / tilesPerB;
    const int t0  = (blockIdx.x % tilesPerB) * BLOCK;

    const float* xb = x + (size_t)b * T * 2;

    // Stage 304-sample window (circular wrap); powers computed once per sample
    for (int j = tid; j < WIN; j += BLOCK) {
        int t = t0 - HALO + j;
        if (t < 0)  t += T;
        if (t >= T) t -= T;
        const float2 z = *(const float2*)(xb + 2 * t);
        float a2 = z.x * z.x + z.y * z.y;
        float a  = sqrtf(a2);
        sZ[j] = z;
        sP[j] = make_float4(a, a * a2, a * a2 * a2, 0.0f);
    }
    __syncthreads();

    // Packed accumulators: .xy hold k=1,k=3 partials; scalar holds k=5.
    v2f   cB2[LL], cC2[LL];
    float cB5[LL], cC5[LL];

    // A-term seeds the B-accumulators (same x1 multiplier)
    #pragma unroll
    for (int l = 0; l < LL; ++l) {
        const float4 p = sP[tid + l + 12];
        const v2f pxy = { p.x, p.y };
        const v2f av  = { Ac[l * NKK + 0], Ac[l * NKK + 1] };
        cB2[l] = av * pxy;
        cB5[l] = Ac[l * NKK + 2] * p.z;
        cC2[l] = (v2f){ 0.0f, 0.0f };
        cC5[l] = 0.0f;
    }

    // d = l + m in [0,23]; one b128 power fetch per d per term.
    // Fully unrolled: coefficient offsets are compile-time constants ->
    // wave-uniform s_load pairs feed v_pk_fma_f32 directly.
    #pragma unroll
    for (int d = 0; d < LL + MM - 1; ++d) {
        const float4 p = sP[tid + d];               // B-term powers (offset d-24)
        const float4 q = sP[tid + d + HALO];        // C-term powers (offset d)
        const v2f pxy = { p.x, p.y };
        const v2f qxy = { q.x, q.y };
        #pragma unroll
        for (int l = 0; l < LL; ++l) {
            const int m = d - l;
            if (m >= 0 && m < MM) {                 // folds at compile time
                const float* bp = Bc + (l * MM + m) * NKK;
                const v2f bcv = { bp[0], bp[1] };
                cB2[l] += bcv * pxy;                // v_pk_fma_f32
                cB5[l] += bp[2] * p.z;
                const float* cp = Cc + (l * MM + m) * NKK;
                const v2f ccv = { cp[0], cp[1] };
                cC2[l] += ccv * qxy;                // v_pk_fma_f32
                cC5[l] += cp[2] * q.z;
            }
        }
    }

    // Epilogue: fold packed partials, then packed (re,im) accumulate
    v2f acc = { 0.0f, 0.0f };
    #pragma unroll
    for (int l = 0; l < LL; ++l) {
        const float cb = cB2[l].x + cB2[l].y + cB5[l];
        const float cc = cC2[l].x + cC2[l].y + cC5[l];
        const float2 z1 = sZ[tid + l + 12];
        const float2 z3 = sZ[tid + l + 36];
        const v2f z1v = { z1.x, z1.y };
        const v2f z3v = { z3.x, z3.y };
        acc += z1v * (v2f){ cb, cb };               // v_pk_fma_f32 (broadcast)
        acc += z3v * (v2f){ cc, cc };
    }

    const int t = t0 + tid;
    if (t < T) {
        float2* op = (float2*)(out + ((size_t)b * T + t) * 2);
        *op = make_float2(acc.x, acc.y);            // global_store_dwordx2
    }
}

extern "C" void kernel_launch(void* const* d_in, const int* in_sizes, int n_in,
                              void* d_out, int out_size, void* d_ws, size_t ws_size,
                              hipStream_t stream)
{
    // Inputs: x (B,T,2) f32, h_0 (B,16) f32 [unused], A_kl (L,NK),
    // B_klm (L,M,NK), C_klm (L,M,NK)
    const float* x  = (const float*)d_in[0];
    const float* Ac = (const float*)d_in[2];
    const float* Bc = (const float*)d_in[3];
    const float* Cc = (const float*)d_in[4];
    float* out = (float*)d_out;

    const int Bsz = in_sizes[1] / 16;               // h_0 is (B,16)
    const int T   = in_sizes[0] / (2 * Bsz);        // x is (B,T,2)
    const int tilesPerB = (T + BLOCK - 1) / BLOCK;  // 32 for T=8192

    dim3 grid(Bsz * tilesPerB);                     // 512 blocks
    dim3 block(BLOCK);
    gmp_kernel<<<grid, block, 0, stream>>>(x, Ac, Bc, Cc, out, T, tilesPerB);
}

// Round 5
// 73.251 us; speedup vs baseline: 1.1640x; 1.1640x over previous
//
#include <hip/hip_runtime.h>
#include <math.h>

// L=13, M=12, ODD_KS=(1,3,5) -> NK=3
#define LL   13
#define MM   12
#define NKK  3
#define BLOCK 256
#define HALO  24                 // window spans [t-24, t+24]
#define WIN  (BLOCK + 2*HALO)    // 304 samples staged per block

// LDS index map (window base t0-24), i = tid:
//   x1(l)    -> Z[i + l + 12]      B-powers(l,m) -> P[i + l + m]
//   x3l(l)   -> Z[i + l + 36]      C-powers(l,m) -> P[i + l + m + 24]
// out = sum_l x1*(A[l].p1 + sum_m B[l,m].P) + x3last*(sum_m C[l,m].P')

__global__ __launch_bounds__(BLOCK)
void gmp_kernel(const float* __restrict__ x,    // (B,T,2)
                const float* __restrict__ Ac,   // (L,NK)
                const float* __restrict__ Bc,   // (L,M,NK)
                const float* __restrict__ Cc,   // (L,M,NK)
                float* __restrict__ out,        // (B,T,2)
                int T, int tilesPerB)
{
    __shared__ float4 sP[WIN];   // {a, a^3, a^5, 0} -> ds_read_b128
    __shared__ float2 sZ[WIN];   // {re, im}         -> ds_read_b64

    const int tid = threadIdx.x;
    const int b   = blockIdx.x / tilesPerB;
    const int t0  = (blockIdx.x % tilesPerB) * BLOCK;

    const float* xb = x + (size_t)b * T * 2;

    // Stage 304-sample window (circular wrap); powers computed once per sample
    for (int j = tid; j < WIN; j += BLOCK) {
        int t = t0 - HALO + j;
        if (t < 0)  t += T;
        if (t >= T) t -= T;
        const float2 z = *(const float2*)(xb + 2 * t);
        float a2 = z.x * z.x + z.y * z.y;
        float a  = sqrtf(a2);
        sZ[j] = z;
        sP[j] = make_float4(a, a * a2, a * a2 * a2, 0.0f);
    }
    __syncthreads();

    // Per-tap coefficient accumulators (compile-time indexed -> registers)
    float cB[LL], cC[LL];
    #pragma unroll
    for (int l = 0; l < LL; ++l) {
        const float4 p = sP[tid + l + 12];          // |x1| powers
        cB[l] = Ac[l * NKK + 0] * p.x
              + Ac[l * NKK + 1] * p.y
              + Ac[l * NKK + 2] * p.z;
        cC[l] = 0.0f;
    }

    // d = l + m in [0,23]; one b128 power fetch per d per term.
    // Fully unrolled: every coefficient offset is a compile-time constant
    // -> wave-uniform s_load broadcasts, zero VALU address math.
    #pragma unroll
    for (int d = 0; d < LL + MM - 1; ++d) {
        const float4 p = sP[tid + d];               // B-term powers (offset d-24)
        const float4 q = sP[tid + d + HALO];        // C-term powers (offset d)
        #pragma unroll
        for (int l = 0; l < LL; ++l) {
            const int m = d - l;
            if (m >= 0 && m < MM) {                 // folds at compile time
                const float* bp = Bc + (l * MM + m) * NKK;
                cB[l] += bp[0] * p.x + bp[1] * p.y + bp[2] * p.z;
                const float* cp = Cc + (l * MM + m) * NKK;
                cC[l] += cp[0] * q.x + cp[1] * q.y + cp[2] * q.z;
            }
        }
    }

    // Complex epilogue: sum_l x1*cB[l] + x3_last*cC[l]
    float sr = 0.0f, si = 0.0f;
    #pragma unroll
    for (int l = 0; l < LL; ++l) {
        const float2 z1 = sZ[tid + l + 12];
        const float2 z3 = sZ[tid + l + 36];
        sr += z1.x * cB[l] + z3.x * cC[l];
        si += z1.y * cB[l] + z3.y * cC[l];
    }

    const int t = t0 + tid;
    if (t < T) {
        float2* op = (float2*)(out + ((size_t)b * T + t) * 2);
        *op = make_float2(sr, si);                  // global_store_dwordx2
    }
}

extern "C" void kernel_launch(void* const* d_in, const int* in_sizes, int n_in,
                              void* d_out, int out_size, void* d_ws, size_t ws_size,
                              hipStream_t stream)
{
    // Inputs: x (B,T,2) f32, h_0 (B,16) f32 [unused], A_kl (L,NK),
    // B_klm (L,M,NK), C_klm (L,M,NK)
    const float* x  = (const float*)d_in[0];
    const float* Ac = (const float*)d_in[2];
    const float* Bc = (const float*)d_in[3];
    const float* Cc = (const float*)d_in[4];
    float* out = (float*)d_out;

    const int Bsz = in_sizes[1] / 16;               // h_0 is (B,16)
    const int T   = in_sizes[0] / (2 * Bsz);        // x is (B,T,2)
    const int tilesPerB = (T + BLOCK - 1) / BLOCK;  // 32 for T=8192

    dim3 grid(Bsz * tilesPerB);                     // 512 blocks
    dim3 block(BLOCK);
    gmp_kernel<<<grid, block, 0, stream>>>(x, Ac, Bc, Cc, out, T, tilesPerB);
}